// Round 4
// baseline (2283.065 us; speedup 1.0000x reference)
//
#include <hip/hip_runtime.h>
#include <math.h>

typedef float v4 __attribute__((ext_vector_type(4)));

#define NN 100000   // nodes
#define NE 100000   // events
#define MD 128      // MEM_D
#define GD 384      // 3*MEM_D
#define MSGD 512    // MSG_D
#define BN 64       // nodes per block (k_main)

// ---------------------------------------------------------------------------
// ws layout (ints):
//   [0,NN)      cnt      (zeroed)
//   [NN,2NN)    cur      (zeroed)
//   [2NN,3NN)   tmax     (zeroed; t>=0 so 0-init safe, only read where cnt>0)
//   [3NN]       total    (zeroed)
//   [3NN+1]     loss_acc (zeroed, float)
//   [Z0,Z0+NN)        offs
//   [Z0+NN,Z0+NN+3NE) entries
//   then tenc: NE*64 floats (16B-aligned: (300032+100000+300000)*4 % 16 == 0)
// ---------------------------------------------------------------------------
#define Z0 300032

// -------------------- CSR build: counts + segment-max(t) -------------------
__global__ __launch_bounds__(256)
void k_count(const int* __restrict__ src, const int* __restrict__ dst,
             const int* __restrict__ prod, const int* __restrict__ t,
             int* __restrict__ cnt, int* __restrict__ tmax)
{
  int e = blockIdx.x * 256 + threadIdx.x;
  if (e < NE) {
    int s = src[e], d = dst[e], p = prod[e], tt = t[e];
    atomicAdd(&cnt[s], 1); atomicAdd(&cnt[d], 1); atomicAdd(&cnt[p], 1);
    atomicMax(&tmax[s], tt); atomicMax(&tmax[d], tt); atomicMax(&tmax[p], tt);
  }
}

// -------------------- per-event time encoding ------------------------------
__global__ __launch_bounds__(256)
void k_tenc(const int* __restrict__ src, const int* __restrict__ t,
            const int* __restrict__ lu,
            const float* __restrict__ W_t, const float* __restrict__ b_t,
            float* __restrict__ tenc)
{
  int gid = blockIdx.x * 256 + threadIdx.x;
  int e = gid >> 4, q = gid & 15;        // 16 vec4 per event (64 dims)
  if (e < NE) {
    float tr = (float)(t[e] - lu[src[e]]);
    int j0 = q * 4;
    v4 v;
    v.x = cosf(tr * W_t[j0 + 0] + b_t[j0 + 0]);
    v.y = cosf(tr * W_t[j0 + 1] + b_t[j0 + 1]);
    v.z = cosf(tr * W_t[j0 + 2] + b_t[j0 + 2]);
    v.w = cosf(tr * W_t[j0 + 3] + b_t[j0 + 3]);
    *reinterpret_cast<v4*>(&tenc[(size_t)e * 64 + j0]) = v;
  }
}

// -------------------- segment offsets via wave-aggregated alloc ------------
// Segment order in entries[] is arbitrary (alloc order), which is fine.
__global__ __launch_bounds__(256)
void k_alloc(const int* __restrict__ cnt, int* __restrict__ offs,
             int* __restrict__ total)
{
  int g = blockIdx.x * 256 + threadIdx.x;
  int lane = threadIdx.x & 63;
  int val = (g < NN) ? cnt[g] : 0;
  int x = val;                                  // wave-inclusive scan
  #pragma unroll
  for (int o = 1; o < 64; o <<= 1) {
    int y = __shfl_up(x, o);
    if (lane >= o) x += y;
  }
  int base = 0;
  if (lane == 63) base = atomicAdd(total, x);   // one atomic per wave
  base = __shfl(base, 63);
  if (g < NN) offs[g] = base + x - val;         // exclusive within wave
}

// -------------------- fill CSR entries -------------------------------------
__global__ __launch_bounds__(256)
void k_fill(const int* __restrict__ src, const int* __restrict__ dst,
            const int* __restrict__ prod,
            const int* __restrict__ offs, int* __restrict__ cur,
            int* __restrict__ entries)
{
  int e = blockIdx.x * 256 + threadIdx.x;
  if (e < NE) {
    int n, p;
    n = src[e];  p = atomicAdd(&cur[n], 1); entries[offs[n] + p] = e;
    n = dst[e];  p = atomicAdd(&cur[n], 1); entries[offs[n] + p] = e;
    n = prod[e]; p = atomicAdd(&cur[n], 1); entries[offs[n] + p] = e;
  }
}

// ---------------------------------------------------------------------------
// Fused main kernel: per 64-node tile,
//   sum_msg chunks (4 x 128) gathered+summed into LDS -> GEMM with W_ih
//   -> scale by 1/count -> + h @ W_hh (n-gate split) -> GRU -> outputs+loss.
// ---------------------------------------------------------------------------
__global__ __launch_bounds__(256)
void k_main(const int* __restrict__ src, const int* __restrict__ dst,
            const int* __restrict__ prod,
            const float* __restrict__ raw, const float* __restrict__ mem,
            const int* __restrict__ lu, const float* __restrict__ init_mem,
            const float* __restrict__ W_ih, const float* __restrict__ W_hh,
            const float* __restrict__ b_ih, const float* __restrict__ b_hh,
            const int* __restrict__ cnt, const int* __restrict__ tmax,
            const int* __restrict__ offs, const int* __restrict__ entries,
            const float* __restrict__ tenc,
            float* __restrict__ out_mem, float* __restrict__ out_lu,
            float* __restrict__ loss_acc)
{
  __shared__ float hs[BN][MD];     // h tile (persists)
  __shared__ float ms[BN][MD];     // current sum_msg k-chunk
  __shared__ int s_off[BN], s_len[BN];
  const int tid = threadIdx.x;
  const int n0 = blockIdx.x * BN;

  if (tid < BN) {
    int node = min(n0 + tid, NN - 1);
    s_off[tid] = offs[node];
    s_len[tid] = cnt[node];
  }
  #pragma unroll
  for (int it = 0; it < 8; ++it) {           // h tile load
    int idx = tid + it * 256;
    int n = idx >> 5, q = idx & 31;
    int node = min(n0 + n, NN - 1);
    const float* sp = (lu[node] == -1) ? init_mem : mem;
    *reinterpret_cast<v4*>(&hs[n][q * 4]) =
        *reinterpret_cast<const v4*>(sp + (size_t)node * MD + q * 4);
  }

  const int tc = tid & 31;   // cols c = j*32 + tc
  const int te = tid >> 5;   // nodes te*8 .. te*8+7

  float acc[8][12];          // gi (then +gh for r,z cols)
  float accn[8][4];          // gh n-gate cols (kept separate: r multiplies h_n only)
  #pragma unroll
  for (int i = 0; i < 8; ++i) {
    #pragma unroll
    for (int j = 0; j < 12; ++j) acc[i][j] = 0.f;
    #pragma unroll
    for (int j = 0; j < 4; ++j) accn[i][j] = 0.f;
  }

  // ---- 4 k-chunks of sum_msg: Σ mem[src], Σ mem[dst], Σ mem[prod], Σ[raw|tenc]
  for (int ch = 0; ch < 4; ++ch) {
    __syncthreads();   // (ch=0: covers s_off/hs; ch>0: protects ms rewrite)
    const int* ridx = (ch == 0) ? src : (ch == 1) ? dst : prod;
    #pragma unroll
    for (int it = 0; it < 8; ++it) {
      int idx = tid + it * 256;
      int n = idx >> 5, q = idx & 31;
      int off = s_off[n], len = s_len[n];
      v4 sum = {0.f, 0.f, 0.f, 0.f};
      if (ch < 3) {
        for (int k = 0; k < len; ++k) {
          int e = entries[off + k];
          int row = ridx[e];
          v4 v = *reinterpret_cast<const v4*>(mem + (size_t)row * MD + q * 4);
          sum.x += v.x; sum.y += v.y; sum.z += v.z; sum.w += v.w;
        }
      } else if (q < 16) {
        for (int k = 0; k < len; ++k) {
          int e = entries[off + k];
          v4 v = *reinterpret_cast<const v4*>(raw + (size_t)e * 64 + q * 4);
          sum.x += v.x; sum.y += v.y; sum.z += v.z; sum.w += v.w;
        }
      } else {
        for (int k = 0; k < len; ++k) {
          int e = entries[off + k];
          v4 v = *reinterpret_cast<const v4*>(tenc + (size_t)e * 64 + (q - 16) * 4);
          sum.x += v.x; sum.y += v.y; sum.z += v.z; sum.w += v.w;
        }
      }
      *reinterpret_cast<v4*>(&ms[n][q * 4]) = sum;
    }
    __syncthreads();
    const float* Wc = W_ih + ch * MD;        // row stride MSGD
    for (int k4 = 0; k4 < 32; ++k4) {
      v4 a[8];
      #pragma unroll
      for (int i = 0; i < 8; ++i)
        a[i] = *reinterpret_cast<const v4*>(&ms[te * 8 + i][k4 * 4]);
      #pragma unroll
      for (int j = 0; j < 12; ++j) {
        int c = j * 32 + tc;
        v4 w = *reinterpret_cast<const v4*>(Wc + (size_t)c * MSGD + k4 * 4);
        #pragma unroll
        for (int i = 0; i < 8; ++i)
          acc[i][j] += a[i].x * w.x + a[i].y * w.y + a[i].z * w.z + a[i].w * w.w;
      }
    }
  }

  // ---- scale gi by 1/count (aggr = sum/max(count,1); @W is linear)
  #pragma unroll
  for (int i = 0; i < 8; ++i) {
    float inv = 1.f / (float)max(s_len[te * 8 + i], 1);
    #pragma unroll
    for (int j = 0; j < 12; ++j) acc[i][j] *= inv;
  }

  // ---- gh = h @ W_hh^T : r,z cols into acc, n cols into accn
  for (int k4 = 0; k4 < 32; ++k4) {
    v4 a[8];
    #pragma unroll
    for (int i = 0; i < 8; ++i)
      a[i] = *reinterpret_cast<const v4*>(&hs[te * 8 + i][k4 * 4]);
    #pragma unroll
    for (int j = 0; j < 12; ++j) {
      int c = j * 32 + tc;
      v4 w = *reinterpret_cast<const v4*>(W_hh + (size_t)c * MD + k4 * 4);
      #pragma unroll
      for (int i = 0; i < 8; ++i) {
        float dp = a[i].x * w.x + a[i].y * w.y + a[i].z * w.z + a[i].w * w.w;
        if (j < 8) acc[i][j] += dp; else accn[i][j - 8] += dp;
      }
    }
  }

  // ---- GRU epilogue
  float br[4], bz[4], bin_[4], bhn[4];
  #pragma unroll
  for (int j = 0; j < 4; ++j) {
    int d = j * 32 + tc;
    br[j]  = b_ih[d]       + b_hh[d];
    bz[j]  = b_ih[128 + d] + b_hh[128 + d];
    bin_[j] = b_ih[256 + d];
    bhn[j] = b_hh[256 + d];
  }
  float ss = 0.f;
  #pragma unroll
  for (int i = 0; i < 8; ++i) {
    int n = te * 8 + i;
    int node = n0 + n;
    if (node < NN) {
      bool has = s_len[n] > 0;
      #pragma unroll
      for (int j = 0; j < 4; ++j) {
        int d = j * 32 + tc;
        float r = 1.f / (1.f + expf(-(acc[i][j] + br[j])));
        float z = 1.f / (1.f + expf(-(acc[i][j + 4] + bz[j])));
        float h_n = accn[i][j] + bhn[j];
        float nn_ = tanhf(acc[i][j + 8] + bin_[j] + r * h_n);
        float hold = hs[n][d];
        float nh = (1.f - z) * nn_ + z * hold;
        float o = has ? nh : hold;
        out_mem[(size_t)node * MD + d] = o;
        float df = has ? (nh - hold) : 0.f;
        ss += df * df;
      }
    }
  }
  #pragma unroll
  for (int off = 32; off > 0; off >>= 1)
    ss += __shfl_down(ss, off);
  if ((tid & 63) == 0) atomicAdd(loss_acc, ss);

  if (tid < BN) {
    int node = n0 + tid;
    if (node < NN)
      out_lu[node] = (float)(s_len[tid] > 0 ? tmax[node] : lu[node]);
  }
}

__global__ void k_fin(const float* __restrict__ loss_acc, float* __restrict__ out_loss)
{
  out_loss[0] = sqrtf(loss_acc[0]) * (1.0f / (float)NN);
}

// ---------------------------------------------------------------------------
extern "C" void kernel_launch(void* const* d_in, const int* in_sizes, int n_in,
                              void* d_out, int out_size, void* d_ws, size_t ws_size,
                              hipStream_t stream)
{
  const int*   src      = (const int*)d_in[0];
  const int*   dst      = (const int*)d_in[1];
  const int*   prod     = (const int*)d_in[2];
  const int*   t        = (const int*)d_in[3];
  const float* raw      = (const float*)d_in[4];
  const float* mem      = (const float*)d_in[5];
  const int*   lu       = (const int*)d_in[6];
  const float* init_mem = (const float*)d_in[7];
  const float* W_t      = (const float*)d_in[8];
  const float* b_t      = (const float*)d_in[9];
  const float* W_ih     = (const float*)d_in[10];
  const float* W_hh     = (const float*)d_in[11];
  const float* b_ih     = (const float*)d_in[12];
  const float* b_hh     = (const float*)d_in[13];

  int* ws_i    = (int*)d_ws;
  int* cnt     = ws_i;
  int* cur     = ws_i + NN;
  int* tmax    = ws_i + 2 * NN;
  int* total   = ws_i + 3 * NN;
  float* loss  = (float*)(ws_i + 3 * NN + 1);
  int* offs    = ws_i + Z0;
  int* entries = offs + NN;
  float* tenc  = (float*)(entries + 3 * NE);

  hipMemsetAsync(d_ws, 0, (size_t)(3 * NN + 2) * sizeof(int), stream);

  float* out_mem  = (float*)d_out;
  float* out_lu   = out_mem + (size_t)NN * MD;
  float* out_loss = out_lu + NN;

  k_count<<<(NE + 255) / 256, 256, 0, stream>>>(src, dst, prod, t, cnt, tmax);
  k_tenc <<<(NE * 16 + 255) / 256, 256, 0, stream>>>(src, t, lu, W_t, b_t, tenc);
  k_alloc<<<(NN + 255) / 256, 256, 0, stream>>>(cnt, offs, total);
  k_fill <<<(NE + 255) / 256, 256, 0, stream>>>(src, dst, prod, offs, cur, entries);
  k_main <<<(NN + BN - 1) / BN, 256, 0, stream>>>(
      src, dst, prod, raw, mem, lu, init_mem, W_ih, W_hh, b_ih, b_hh,
      cnt, tmax, offs, entries, tenc, out_mem, out_lu, loss);
  k_fin  <<<1, 1, 0, stream>>>(loss, out_loss);
}

// Round 5
// 2059.043 us; speedup vs baseline: 1.1088x; 1.1088x over previous
//
#include <hip/hip_runtime.h>
#include <math.h>

typedef float v4 __attribute__((ext_vector_type(4)));
typedef unsigned short us4 __attribute__((ext_vector_type(4)));
typedef unsigned short us8 __attribute__((ext_vector_type(8)));

#define NN 100000   // nodes
#define NE 100000   // events
#define MD 128      // MEM_D
#define GD 384      // 3*MEM_D
#define MSGD 512    // MSG_D
#define BN 64       // nodes per block (k_gemm)

// ws layout:
//   ints [0,NN) cnt | [NN,2NN) cur | [2NN,3NN) tmax | [3NN] total | [3NN+1] loss
//   ints [Z0,Z0+NN) offs | [Z0+NN,Z0+NN+3NE) entries
//   float tenc[NE*64]   @ byte 2,800,128
//   bf16  aggr[NN*512]  @ byte 28,400,128   (total ~130.8 MB)
#define Z0 300032

static __device__ inline unsigned short f2bf(float f) {
  unsigned u = __builtin_bit_cast(unsigned, f);
  u += 0x7fff + ((u >> 16) & 1);          // RNE
  return (unsigned short)(u >> 16);
}
static __device__ inline float bf2f(unsigned short s) {
  unsigned u = ((unsigned)s) << 16;
  return __builtin_bit_cast(float, u);
}

// -------------------- CSR build: counts + segment-max(t) -------------------
__global__ __launch_bounds__(256)
void k_count(const int* __restrict__ src, const int* __restrict__ dst,
             const int* __restrict__ prod, const int* __restrict__ t,
             int* __restrict__ cnt, int* __restrict__ tmax)
{
  int e = blockIdx.x * 256 + threadIdx.x;
  if (e < NE) {
    int s = src[e], d = dst[e], p = prod[e], tt = t[e];
    atomicAdd(&cnt[s], 1); atomicAdd(&cnt[d], 1); atomicAdd(&cnt[p], 1);
    atomicMax(&tmax[s], tt); atomicMax(&tmax[d], tt); atomicMax(&tmax[p], tt);
  }
}

// -------------------- per-event time encoding ------------------------------
__global__ __launch_bounds__(256)
void k_tenc(const int* __restrict__ src, const int* __restrict__ t,
            const int* __restrict__ lu,
            const float* __restrict__ W_t, const float* __restrict__ b_t,
            float* __restrict__ tenc)
{
  int gid = blockIdx.x * 256 + threadIdx.x;
  int e = gid >> 4, q = gid & 15;
  if (e < NE) {
    float tr = (float)(t[e] - lu[src[e]]);
    int j0 = q * 4;
    v4 v;
    v.x = cosf(tr * W_t[j0 + 0] + b_t[j0 + 0]);
    v.y = cosf(tr * W_t[j0 + 1] + b_t[j0 + 1]);
    v.z = cosf(tr * W_t[j0 + 2] + b_t[j0 + 2]);
    v.w = cosf(tr * W_t[j0 + 3] + b_t[j0 + 3]);
    *reinterpret_cast<v4*>(&tenc[(size_t)e * 64 + j0]) = v;
  }
}

// -------------------- segment offsets via wave-aggregated alloc ------------
__global__ __launch_bounds__(256)
void k_alloc(const int* __restrict__ cnt, int* __restrict__ offs,
             int* __restrict__ total)
{
  int g = blockIdx.x * 256 + threadIdx.x;
  int lane = threadIdx.x & 63;
  int val = (g < NN) ? cnt[g] : 0;
  int x = val;
  #pragma unroll
  for (int o = 1; o < 64; o <<= 1) {
    int y = __shfl_up(x, o);
    if (lane >= o) x += y;
  }
  int base = 0;
  if (lane == 63) base = atomicAdd(total, x);
  base = __shfl(base, 63);
  if (g < NN) offs[g] = base + x - val;
}

// -------------------- fill CSR entries -------------------------------------
__global__ __launch_bounds__(256)
void k_fill(const int* __restrict__ src, const int* __restrict__ dst,
            const int* __restrict__ prod,
            const int* __restrict__ offs, int* __restrict__ cur,
            int* __restrict__ entries)
{
  int e = blockIdx.x * 256 + threadIdx.x;
  if (e < NE) {
    int n, p;
    n = src[e];  p = atomicAdd(&cur[n], 1); entries[offs[n] + p] = e;
    n = dst[e];  p = atomicAdd(&cur[n], 1); entries[offs[n] + p] = e;
    n = prod[e]; p = atomicAdd(&cur[n], 1); entries[offs[n] + p] = e;
  }
}

// ---------------------------------------------------------------------------
// Aggregation: thread = (node, v4-slot of 512-wide msg). No LDS -> full
// occupancy; 2-deep pipeline on the entries->ridx->mem chain. Writes
// aggr = sum/max(cnt,1) as bf16.
// ---------------------------------------------------------------------------
__global__ __launch_bounds__(256)
void k_aggr(const int* __restrict__ src, const int* __restrict__ dst,
            const int* __restrict__ prod,
            const float* __restrict__ raw, const float* __restrict__ mem,
            const float* __restrict__ tenc,
            const int* __restrict__ offs, const int* __restrict__ cnt,
            const int* __restrict__ entries,
            unsigned short* __restrict__ aggr)
{
  const int tid = threadIdx.x;
  const int n = blockIdx.x * 2 + (tid >> 7);      // NN even: no tail
  const int q = tid & 127;                        // v4 slot in [0,128)
  const int off = offs[n];
  const int len = cnt[n];

  v4 sum = {0.f, 0.f, 0.f, 0.f};
  if (q < 96) {
    const int* ridx = (q < 32) ? src : (q < 64) ? dst : prod;
    const int qc = q & 31;
    int e_cur = 0, row_cur = 0;
    if (len > 0) { e_cur = entries[off]; row_cur = ridx[e_cur]; }
    for (int k = 0; k < len; ++k) {
      int e_nxt = 0, row_nxt = 0;
      if (k + 1 < len) { e_nxt = entries[off + k + 1]; row_nxt = ridx[e_nxt]; }
      v4 v = *reinterpret_cast<const v4*>(mem + (size_t)row_cur * MD + qc * 4);
      sum.x += v.x; sum.y += v.y; sum.z += v.z; sum.w += v.w;
      e_cur = e_nxt; row_cur = row_nxt;
    }
    (void)e_cur;
  } else {
    const float* base = (q < 112) ? raw : tenc;
    const int qc = q & 15;
    for (int k = 0; k < len; ++k) {
      int e = entries[off + k];
      v4 v = *reinterpret_cast<const v4*>(base + (size_t)e * 64 + qc * 4);
      sum.x += v.x; sum.y += v.y; sum.z += v.z; sum.w += v.w;
    }
  }
  float inv = 1.f / (float)max(len, 1);
  us4 o;
  o.x = f2bf(sum.x * inv); o.y = f2bf(sum.y * inv);
  o.z = f2bf(sum.z * inv); o.w = f2bf(sum.w * inv);
  *reinterpret_cast<us4*>(aggr + (size_t)n * MSGD + q * 4) = o;
}

// ---------------------------------------------------------------------------
// Dense GEMM + GRU: gi = aggr @ W_ih^T (chunked), gh = h @ W_hh^T, epilogue.
// ---------------------------------------------------------------------------
__global__ __launch_bounds__(256)
void k_gemm(const float* __restrict__ mem, const int* __restrict__ lu,
            const float* __restrict__ init_mem,
            const float* __restrict__ W_ih, const float* __restrict__ W_hh,
            const float* __restrict__ b_ih, const float* __restrict__ b_hh,
            const int* __restrict__ cnt, const int* __restrict__ tmax,
            const unsigned short* __restrict__ aggr,
            float* __restrict__ out_mem, float* __restrict__ out_lu,
            float* __restrict__ loss_acc)
{
  __shared__ float hs[BN][MD];
  __shared__ float ms[BN][MD];
  __shared__ int s_len[BN];
  const int tid = threadIdx.x;
  const int n0 = blockIdx.x * BN;

  if (tid < BN) s_len[tid] = cnt[min(n0 + tid, NN - 1)];
  #pragma unroll
  for (int it = 0; it < 8; ++it) {
    int idx = tid + it * 256;
    int n = idx >> 5, q = idx & 31;
    int node = min(n0 + n, NN - 1);
    const float* sp = (lu[node] == -1) ? init_mem : mem;
    *reinterpret_cast<v4*>(&hs[n][q * 4]) =
        *reinterpret_cast<const v4*>(sp + (size_t)node * MD + q * 4);
  }

  const int tc = tid & 31;
  const int te = tid >> 5;

  float acc[8][12];
  float accn[8][4];
  #pragma unroll
  for (int i = 0; i < 8; ++i) {
    #pragma unroll
    for (int j = 0; j < 12; ++j) acc[i][j] = 0.f;
    #pragma unroll
    for (int j = 0; j < 4; ++j) accn[i][j] = 0.f;
  }

  // ---- gi: 4 k-chunks of 128 from bf16 aggr
  for (int ch = 0; ch < 4; ++ch) {
    __syncthreads();
    #pragma unroll
    for (int it = 0; it < 4; ++it) {               // 1024 groups of 8 elems
      int idx = tid + it * 256;
      int n = idx >> 4, g = idx & 15;
      int node = min(n0 + n, NN - 1);
      us8 u = *reinterpret_cast<const us8*>(
          aggr + (size_t)node * MSGD + ch * MD + g * 8);
      float* dp = &ms[n][g * 8];
      #pragma unroll
      for (int x = 0; x < 8; ++x) dp[x] = bf2f(u[x]);
    }
    __syncthreads();
    const float* Wc = W_ih + ch * MD;
    for (int k4 = 0; k4 < 32; ++k4) {
      v4 a[8];
      #pragma unroll
      for (int i = 0; i < 8; ++i)
        a[i] = *reinterpret_cast<const v4*>(&ms[te * 8 + i][k4 * 4]);
      #pragma unroll
      for (int j = 0; j < 12; ++j) {
        int c = j * 32 + tc;
        v4 w = *reinterpret_cast<const v4*>(Wc + (size_t)c * MSGD + k4 * 4);
        #pragma unroll
        for (int i = 0; i < 8; ++i)
          acc[i][j] += a[i].x * w.x + a[i].y * w.y + a[i].z * w.z + a[i].w * w.w;
      }
    }
  }

  // ---- gh = h @ W_hh^T : r,z cols into acc, n cols into accn
  for (int k4 = 0; k4 < 32; ++k4) {
    v4 a[8];
    #pragma unroll
    for (int i = 0; i < 8; ++i)
      a[i] = *reinterpret_cast<const v4*>(&hs[te * 8 + i][k4 * 4]);
    #pragma unroll
    for (int j = 0; j < 12; ++j) {
      int c = j * 32 + tc;
      v4 w = *reinterpret_cast<const v4*>(W_hh + (size_t)c * MD + k4 * 4);
      #pragma unroll
      for (int i = 0; i < 8; ++i) {
        float dp = a[i].x * w.x + a[i].y * w.y + a[i].z * w.z + a[i].w * w.w;
        if (j < 8) acc[i][j] += dp; else accn[i][j - 8] += dp;
      }
    }
  }

  // ---- GRU epilogue
  float br[4], bz[4], bin_[4], bhn[4];
  #pragma unroll
  for (int j = 0; j < 4; ++j) {
    int d = j * 32 + tc;
    br[j]   = b_ih[d]       + b_hh[d];
    bz[j]   = b_ih[128 + d] + b_hh[128 + d];
    bin_[j] = b_ih[256 + d];
    bhn[j]  = b_hh[256 + d];
  }
  float ss = 0.f;
  #pragma unroll
  for (int i = 0; i < 8; ++i) {
    int n = te * 8 + i;
    int node = n0 + n;
    if (node < NN) {
      bool has = s_len[n] > 0;
      #pragma unroll
      for (int j = 0; j < 4; ++j) {
        int d = j * 32 + tc;
        float r = 1.f / (1.f + expf(-(acc[i][j] + br[j])));
        float z = 1.f / (1.f + expf(-(acc[i][j + 4] + bz[j])));
        float h_n = accn[i][j] + bhn[j];
        float nn_ = tanhf(acc[i][j + 8] + bin_[j] + r * h_n);
        float hold = hs[n][d];
        float nh = (1.f - z) * nn_ + z * hold;
        float o = has ? nh : hold;
        out_mem[(size_t)node * MD + d] = o;
        float df = has ? (nh - hold) : 0.f;
        ss += df * df;
      }
    }
  }
  #pragma unroll
  for (int off = 32; off > 0; off >>= 1)
    ss += __shfl_down(ss, off);
  if ((tid & 63) == 0) atomicAdd(loss_acc, ss);

  if (tid < BN) {
    int node = n0 + tid;
    if (node < NN)
      out_lu[node] = (float)(s_len[tid] > 0 ? tmax[node] : lu[node]);
  }
}

__global__ void k_fin(const float* __restrict__ loss_acc, float* __restrict__ out_loss)
{
  out_loss[0] = sqrtf(loss_acc[0]) * (1.0f / (float)NN);
}

// ---------------------------------------------------------------------------
extern "C" void kernel_launch(void* const* d_in, const int* in_sizes, int n_in,
                              void* d_out, int out_size, void* d_ws, size_t ws_size,
                              hipStream_t stream)
{
  const int*   src      = (const int*)d_in[0];
  const int*   dst      = (const int*)d_in[1];
  const int*   prod     = (const int*)d_in[2];
  const int*   t        = (const int*)d_in[3];
  const float* raw      = (const float*)d_in[4];
  const float* mem      = (const float*)d_in[5];
  const int*   lu       = (const int*)d_in[6];
  const float* init_mem = (const float*)d_in[7];
  const float* W_t      = (const float*)d_in[8];
  const float* b_t      = (const float*)d_in[9];
  const float* W_ih     = (const float*)d_in[10];
  const float* W_hh     = (const float*)d_in[11];
  const float* b_ih     = (const float*)d_in[12];
  const float* b_hh     = (const float*)d_in[13];

  int* ws_i    = (int*)d_ws;
  int* cnt     = ws_i;
  int* cur     = ws_i + NN;
  int* tmax    = ws_i + 2 * NN;
  int* total   = ws_i + 3 * NN;
  float* loss  = (float*)(ws_i + 3 * NN + 1);
  int* offs    = ws_i + Z0;
  int* entries = offs + NN;
  float* tenc  = (float*)(entries + 3 * NE);           // byte 2,800,128
  unsigned short* aggr = (unsigned short*)(tenc + (size_t)NE * 64);  // byte 28,400,128

  hipMemsetAsync(d_ws, 0, (size_t)(3 * NN + 2) * sizeof(int), stream);

  float* out_mem  = (float*)d_out;
  float* out_lu   = out_mem + (size_t)NN * MD;
  float* out_loss = out_lu + NN;

  k_count<<<(NE + 255) / 256, 256, 0, stream>>>(src, dst, prod, t, cnt, tmax);
  k_tenc <<<(NE * 16 + 255) / 256, 256, 0, stream>>>(src, t, lu, W_t, b_t, tenc);
  k_alloc<<<(NN + 255) / 256, 256, 0, stream>>>(cnt, offs, total);
  k_fill <<<(NE + 255) / 256, 256, 0, stream>>>(src, dst, prod, offs, cur, entries);
  k_aggr <<<NN / 2, 256, 0, stream>>>(src, dst, prod, raw, mem, tenc,
                                      offs, cnt, entries, aggr);
  k_gemm <<<(NN + BN - 1) / BN, 256, 0, stream>>>(
      mem, lu, init_mem, W_ih, W_hh, b_ih, b_hh,
      cnt, tmax, aggr, out_mem, out_lu, loss);
  k_fin  <<<1, 1, 0, stream>>>(loss, out_loss);
}

// Round 7
// 734.476 us; speedup vs baseline: 3.1084x; 2.8034x over previous
//
#include <hip/hip_runtime.h>
#include <math.h>

typedef float v4 __attribute__((ext_vector_type(4)));
typedef unsigned short us4 __attribute__((ext_vector_type(4)));
typedef unsigned short us8 __attribute__((ext_vector_type(8)));
typedef __bf16 bf16x8 __attribute__((ext_vector_type(8)));
typedef float f32x4 __attribute__((ext_vector_type(4)));

#define NN 100000   // nodes
#define NE 100000   // events
#define MD 128      // MEM_D
#define GD 384      // 3*MEM_D
#define MSGD 512    // MSG_D

// ws layout:
//   ints [0,NN) cnt | [NN,2NN) cur | [2NN,3NN) tmax | [3NN] total | [3NN+1] loss
//   ints [Z0,Z0+NN) offs | [Z0+NN,Z0+NN+3NE) entries       (ends at int 700032)
//   bf16 tenc[NE*64]    @ byte   2,800,128
//   bf16 aggr[NN*512]   @ byte  15,600,128
//   bf16 hbf [NN*128]   @ byte 118,000,128
//   bf16 wih [384*512]  @ byte 143,600,128
//   bf16 whh [384*128]  @ byte 143,993,344   (total ~144.1 MB)
#define Z0 300032

static __device__ inline unsigned short f2bf(float f) {
  unsigned u = __builtin_bit_cast(unsigned, f);
  u += 0x7fff + ((u >> 16) & 1);          // RNE
  return (unsigned short)(u >> 16);
}
static __device__ inline float bf2f(unsigned short s) {
  unsigned u = ((unsigned)s) << 16;
  return __builtin_bit_cast(float, u);
}

// -------------------- CSR build: counts + segment-max(t) -------------------
__global__ __launch_bounds__(256)
void k_count(const int* __restrict__ src, const int* __restrict__ dst,
             const int* __restrict__ prod, const int* __restrict__ t,
             int* __restrict__ cnt, int* __restrict__ tmax)
{
  int e = blockIdx.x * 256 + threadIdx.x;
  if (e < NE) {
    int s = src[e], d = dst[e], p = prod[e], tt = t[e];
    atomicAdd(&cnt[s], 1); atomicAdd(&cnt[d], 1); atomicAdd(&cnt[p], 1);
    atomicMax(&tmax[s], tt); atomicMax(&tmax[d], tt); atomicMax(&tmax[p], tt);
  }
}

// -------------------- per-event time encoding (bf16 out) -------------------
__global__ __launch_bounds__(256)
void k_tenc(const int* __restrict__ src, const int* __restrict__ t,
            const int* __restrict__ lu,
            const float* __restrict__ W_t, const float* __restrict__ b_t,
            unsigned short* __restrict__ tenc)
{
  int gid = blockIdx.x * 256 + threadIdx.x;
  int e = gid >> 4, q = gid & 15;
  if (e < NE) {
    float tr = (float)(t[e] - lu[src[e]]);
    int j0 = q * 4;
    us4 o;
    o.x = f2bf(cosf(tr * W_t[j0 + 0] + b_t[j0 + 0]));
    o.y = f2bf(cosf(tr * W_t[j0 + 1] + b_t[j0 + 1]));
    o.z = f2bf(cosf(tr * W_t[j0 + 2] + b_t[j0 + 2]));
    o.w = f2bf(cosf(tr * W_t[j0 + 3] + b_t[j0 + 3]));
    *reinterpret_cast<us4*>(&tenc[(size_t)e * 64 + j0]) = o;
  }
}

// -------------------- segment offsets via wave-aggregated alloc ------------
__global__ __launch_bounds__(256)
void k_alloc(const int* __restrict__ cnt, int* __restrict__ offs,
             int* __restrict__ total)
{
  int g = blockIdx.x * 256 + threadIdx.x;
  int lane = threadIdx.x & 63;
  int val = (g < NN) ? cnt[g] : 0;
  int x = val;
  #pragma unroll
  for (int o = 1; o < 64; o <<= 1) {
    int y = __shfl_up(x, o);
    if (lane >= o) x += y;
  }
  int base = 0;
  if (lane == 63) base = atomicAdd(total, x);
  base = __shfl(base, 63);
  if (g < NN) offs[g] = base + x - val;
}

// -------------------- fill CSR entries -------------------------------------
__global__ __launch_bounds__(256)
void k_fill(const int* __restrict__ src, const int* __restrict__ dst,
            const int* __restrict__ prod,
            const int* __restrict__ offs, int* __restrict__ cur,
            int* __restrict__ entries)
{
  int e = blockIdx.x * 256 + threadIdx.x;
  if (e < NE) {
    int n, p;
    n = src[e];  p = atomicAdd(&cur[n], 1); entries[offs[n] + p] = e;
    n = dst[e];  p = atomicAdd(&cur[n], 1); entries[offs[n] + p] = e;
    n = prod[e]; p = atomicAdd(&cur[n], 1); entries[offs[n] + p] = e;
  }
}

// -------------------- bf16 conversions: W_ih, W_hh, h ----------------------
__global__ __launch_bounds__(256)
void k_conv(const float* __restrict__ W_ih, const float* __restrict__ W_hh,
            const float* __restrict__ mem, const float* __restrict__ init_mem,
            const int* __restrict__ lu,
            unsigned short* __restrict__ wih, unsigned short* __restrict__ whh,
            unsigned short* __restrict__ hbf)
{
  const int NWIH = 384 * 512 / 8;     // 24576
  const int NWHH = 384 * 128 / 8;     // 6144
  int gid = blockIdx.x * 256 + threadIdx.x;
  const float* s;
  unsigned short* o;
  if (gid < NWIH) {
    s = W_ih + (size_t)gid * 8;  o = wih + (size_t)gid * 8;
  } else if (gid < NWIH + NWHH) {
    int k = gid - NWIH;
    s = W_hh + (size_t)k * 8;    o = whh + (size_t)k * 8;
  } else {
    int k = gid - NWIH - NWHH;   // [0, NN*16)
    int node = k >> 4;
    const float* hb = (lu[node] == -1) ? init_mem : mem;
    s = hb + (size_t)node * MD + (k & 15) * 8;
    o = hbf + (size_t)k * 8;
  }
  v4 a0 = *reinterpret_cast<const v4*>(s);
  v4 a1 = *reinterpret_cast<const v4*>(s + 4);
  us8 u;
  u[0] = f2bf(a0.x); u[1] = f2bf(a0.y); u[2] = f2bf(a0.z); u[3] = f2bf(a0.w);
  u[4] = f2bf(a1.x); u[5] = f2bf(a1.y); u[6] = f2bf(a1.z); u[7] = f2bf(a1.w);
  *reinterpret_cast<us8*>(o) = u;
}

// ---------------------------------------------------------------------------
// Aggregation: thread = (node, v4-slot of 512-wide msg). Writes bf16 aggr.
// ---------------------------------------------------------------------------
__global__ __launch_bounds__(256)
void k_aggr(const int* __restrict__ src, const int* __restrict__ dst,
            const int* __restrict__ prod,
            const float* __restrict__ raw, const float* __restrict__ mem,
            const unsigned short* __restrict__ tenc,
            const int* __restrict__ offs, const int* __restrict__ cnt,
            const int* __restrict__ entries,
            unsigned short* __restrict__ aggr)
{
  const int tid = threadIdx.x;
  const int n = blockIdx.x * 2 + (tid >> 7);
  const int q = tid & 127;
  const int off = offs[n];
  const int len = cnt[n];

  v4 sum = {0.f, 0.f, 0.f, 0.f};
  if (q < 96) {
    const int* ridx = (q < 32) ? src : (q < 64) ? dst : prod;
    const int qc = q & 31;
    int e_cur = 0, row_cur = 0;
    if (len > 0) { e_cur = entries[off]; row_cur = ridx[e_cur]; }
    for (int k = 0; k < len; ++k) {
      int e_nxt = 0, row_nxt = 0;
      if (k + 1 < len) { e_nxt = entries[off + k + 1]; row_nxt = ridx[e_nxt]; }
      v4 v = *reinterpret_cast<const v4*>(mem + (size_t)row_cur * MD + qc * 4);
      sum.x += v.x; sum.y += v.y; sum.z += v.z; sum.w += v.w;
      e_cur = e_nxt; row_cur = row_nxt;
    }
    (void)e_cur;
  } else if (q < 112) {
    const int qc = q & 15;
    for (int k = 0; k < len; ++k) {
      int e = entries[off + k];
      v4 v = *reinterpret_cast<const v4*>(raw + (size_t)e * 64 + qc * 4);
      sum.x += v.x; sum.y += v.y; sum.z += v.z; sum.w += v.w;
    }
  } else {
    const int qc = q & 15;
    for (int k = 0; k < len; ++k) {
      int e = entries[off + k];
      us4 u = *reinterpret_cast<const us4*>(tenc + (size_t)e * 64 + qc * 4);
      sum.x += bf2f(u.x); sum.y += bf2f(u.y);
      sum.z += bf2f(u.z); sum.w += bf2f(u.w);
    }
  }
  float inv = 1.f / (float)max(len, 1);
  us4 o;
  o.x = f2bf(sum.x * inv); o.y = f2bf(sum.y * inv);
  o.z = f2bf(sum.z * inv); o.w = f2bf(sum.w * inv);
  *reinterpret_cast<us4*>(aggr + (size_t)n * MSGD + q * 4) = o;
}

// ---------------------------------------------------------------------------
// MFMA dual-GEMM + GRU.  Block = 256 threads = 4 waves, 64 nodes.
// Wave w owns d-range [w*32, w*32+32): 2 d-frags x 3 gates x 4 row-frags.
// A-frag: lane l holds A[l&15][k0+(l>>4)*8 + i];  B-frag: B[k0+(l>>4)*8+i][l&15]
//   = Wrow[l&15] contiguous in k.  D: col=l&15, row=(l>>4)*4+reg (m89).
// ---------------------------------------------------------------------------
__global__ __launch_bounds__(256)
void k_mfma(const unsigned short* __restrict__ aggr,
            const unsigned short* __restrict__ hbf,
            const unsigned short* __restrict__ wih,
            const unsigned short* __restrict__ whh,
            const float* __restrict__ mem, const float* __restrict__ init_mem,
            const int* __restrict__ lu,
            const float* __restrict__ b_ih, const float* __restrict__ b_hh,
            const int* __restrict__ cnt, const int* __restrict__ tmax,
            float* __restrict__ out_mem, float* __restrict__ out_lu,
            float* __restrict__ loss_acc)
{
  __shared__ float s_inv[64];
  __shared__ int s_sel[64], s_has[64];
  const int tid = threadIdx.x;
  const int n0 = blockIdx.x * 64;

  if (tid < 64) {
    int node = min(n0 + tid, NN - 1);
    int c = cnt[node];
    s_inv[tid] = 1.f / (float)max(c, 1);
    s_has[tid] = (c > 0);
    s_sel[tid] = (lu[node] == -1);
    if (n0 + tid < NN)
      out_lu[node] = (float)(c > 0 ? tmax[node] : lu[node]);
  }
  __syncthreads();

  const int w  = tid >> 6;
  const int l  = tid & 63;
  const int ln = l & 15;
  const int lg = l >> 4;

  f32x4 acc1[3][4][2];        // gates r,z,(i_n) x row-frag x d-frag
  f32x4 accNh[4][2];          // h_n
  #pragma unroll
  for (int g = 0; g < 3; ++g)
    #pragma unroll
    for (int rf = 0; rf < 4; ++rf)
      #pragma unroll
      for (int df = 0; df < 2; ++df)
        acc1[g][rf][df] = (f32x4){0.f, 0.f, 0.f, 0.f};
  #pragma unroll
  for (int rf = 0; rf < 4; ++rf)
    #pragma unroll
    for (int df = 0; df < 2; ++df)
      accNh[rf][df] = (f32x4){0.f, 0.f, 0.f, 0.f};

  int rowA[4];
  #pragma unroll
  for (int rf = 0; rf < 4; ++rf) rowA[rf] = min(n0 + rf * 16 + ln, NN - 1);

  // ---- GEMM1: gi = aggr @ W_ih^T   (K = 512, 16 k-steps)
  for (int ks = 0; ks < 16; ++ks) {
    bf16x8 a[4];
    #pragma unroll
    for (int rf = 0; rf < 4; ++rf)
      a[rf] = *reinterpret_cast<const bf16x8*>(
          aggr + (size_t)rowA[rf] * MSGD + ks * 32 + lg * 8);
    #pragma unroll
    for (int g = 0; g < 3; ++g) {
      #pragma unroll
      for (int df = 0; df < 2; ++df) {
        int col = g * 128 + w * 32 + df * 16 + ln;
        bf16x8 b = *reinterpret_cast<const bf16x8*>(
            wih + (size_t)col * MSGD + ks * 32 + lg * 8);
        #pragma unroll
        for (int rf = 0; rf < 4; ++rf)
          acc1[g][rf][df] = __builtin_amdgcn_mfma_f32_16x16x32_bf16(
              a[rf], b, acc1[g][rf][df], 0, 0, 0);
      }
    }
  }

  // ---- scale gi by 1/count (per output row)
  float inv[4][4];
  #pragma unroll
  for (int rf = 0; rf < 4; ++rf)
    #pragma unroll
    for (int i = 0; i < 4; ++i)
      inv[rf][i] = s_inv[rf * 16 + lg * 4 + i];
  #pragma unroll
  for (int g = 0; g < 3; ++g)
    #pragma unroll
    for (int rf = 0; rf < 4; ++rf)
      #pragma unroll
      for (int df = 0; df < 2; ++df)
        #pragma unroll
        for (int i = 0; i < 4; ++i)
          acc1[g][rf][df][i] *= inv[rf][i];

  // ---- GEMM2: gh = h @ W_hh^T   (K = 128, 4 k-steps); n-gate separate
  for (int ks = 0; ks < 4; ++ks) {
    bf16x8 a[4];
    #pragma unroll
    for (int rf = 0; rf < 4; ++rf)
      a[rf] = *reinterpret_cast<const bf16x8*>(
          hbf + (size_t)rowA[rf] * MD + ks * 32 + lg * 8);
    #pragma unroll
    for (int g = 0; g < 3; ++g) {
      #pragma unroll
      for (int df = 0; df < 2; ++df) {
        int col = g * 128 + w * 32 + df * 16 + ln;
        bf16x8 b = *reinterpret_cast<const bf16x8*>(
            whh + (size_t)col * MD + ks * 32 + lg * 8);
        if (g < 2) {
          #pragma unroll
          for (int rf = 0; rf < 4; ++rf)
            acc1[g][rf][df] = __builtin_amdgcn_mfma_f32_16x16x32_bf16(
                a[rf], b, acc1[g][rf][df], 0, 0, 0);
        } else {
          #pragma unroll
          for (int rf = 0; rf < 4; ++rf)
            accNh[rf][df] = __builtin_amdgcn_mfma_f32_16x16x32_bf16(
                a[rf], b, accNh[rf][df], 0, 0, 0);
        }
      }
    }
  }

  // ---- GRU epilogue (all gates in-lane)
  float ss = 0.f;
  #pragma unroll
  for (int df = 0; df < 2; ++df) {
    int d = w * 32 + df * 16 + ln;
    float bir = b_ih[d], biz = b_ih[128 + d], bin_ = b_ih[256 + d];
    float bhr = b_hh[d], bhz = b_hh[128 + d], bhn  = b_hh[256 + d];
    #pragma unroll
    for (int rf = 0; rf < 4; ++rf) {
      #pragma unroll
      for (int i = 0; i < 4; ++i) {
        int nloc = rf * 16 + lg * 4 + i;
        int node = n0 + nloc;
        if (node < NN) {
          const float* hb = s_sel[nloc] ? init_mem : mem;
          float hold = hb[(size_t)node * MD + d];
          float r  = 1.f / (1.f + expf(-(acc1[0][rf][df][i] + bir + bhr)));
          float z  = 1.f / (1.f + expf(-(acc1[1][rf][df][i] + biz + bhz)));
          float hn = accNh[rf][df][i] + bhn;
          float nn_ = tanhf(acc1[2][rf][df][i] + bin_ + r * hn);
          float nh = (1.f - z) * nn_ + z * hold;
          bool has = s_has[nloc] != 0;
          float o = has ? nh : hold;
          out_mem[(size_t)node * MD + d] = o;
          float dv = has ? (nh - hold) : 0.f;
          ss += dv * dv;
        }
      }
    }
  }
  #pragma unroll
  for (int off = 32; off > 0; off >>= 1)
    ss += __shfl_down(ss, off);
  if (l == 0) atomicAdd(loss_acc, ss);
}

__global__ void k_fin(const float* __restrict__ loss_acc, float* __restrict__ out_loss)
{
  out_loss[0] = sqrtf(loss_acc[0]) * (1.0f / (float)NN);
}

// ---------------------------------------------------------------------------
extern "C" void kernel_launch(void* const* d_in, const int* in_sizes, int n_in,
                              void* d_out, int out_size, void* d_ws, size_t ws_size,
                              hipStream_t stream)
{
  const int*   src      = (const int*)d_in[0];
  const int*   dst      = (const int*)d_in[1];
  const int*   prod     = (const int*)d_in[2];
  const int*   t        = (const int*)d_in[3];
  const float* raw      = (const float*)d_in[4];
  const float* mem      = (const float*)d_in[5];
  const int*   lu       = (const int*)d_in[6];
  const float* init_mem = (const float*)d_in[7];
  const float* W_t      = (const float*)d_in[8];
  const float* b_t      = (const float*)d_in[9];
  const float* W_ih     = (const float*)d_in[10];
  const float* W_hh     = (const float*)d_in[11];
  const float* b_ih     = (const float*)d_in[12];
  const float* b_hh     = (const float*)d_in[13];

  int* ws_i    = (int*)d_ws;
  int* cnt     = ws_i;
  int* cur     = ws_i + NN;
  int* tmax    = ws_i + 2 * NN;
  int* total   = ws_i + 3 * NN;
  float* loss  = (float*)(ws_i + 3 * NN + 1);
  int* offs    = ws_i + Z0;
  int* entries = offs + NN;
  unsigned short* tenc = (unsigned short*)(entries + 3 * NE);   // byte 2,800,128
  unsigned short* aggr = tenc + (size_t)NE * 64;                // byte 15,600,128
  unsigned short* hbf  = aggr + (size_t)NN * MSGD;              // byte 118,000,128
  unsigned short* wih  = hbf  + (size_t)NN * MD;                // byte 143,600,128
  unsigned short* whh  = wih  + (size_t)GD * MSGD;              // byte 143,993,344

  hipMemsetAsync(d_ws, 0, (size_t)(3 * NN + 2) * sizeof(int), stream);

  float* out_mem  = (float*)d_out;
  float* out_lu   = out_mem + (size_t)NN * MD;
  float* out_loss = out_lu + NN;

  k_count<<<(NE + 255) / 256, 256, 0, stream>>>(src, dst, prod, t, cnt, tmax);
  k_tenc <<<(NE * 16 + 255) / 256, 256, 0, stream>>>(src, t, lu, W_t, b_t, tenc);
  k_conv <<<(384 * 512 / 8 + 384 * 128 / 8 + NN * MD / 8 + 255) / 256, 256, 0, stream>>>(
      W_ih, W_hh, mem, init_mem, lu, wih, whh, hbf);
  k_alloc<<<(NN + 255) / 256, 256, 0, stream>>>(cnt, offs, total);
  k_fill <<<(NE + 255) / 256, 256, 0, stream>>>(src, dst, prod, offs, cur, entries);
  k_aggr <<<NN / 2, 256, 0, stream>>>(src, dst, prod, raw, mem, tenc,
                                      offs, cnt, entries, aggr);
  k_mfma <<<(NN + 63) / 64, 256, 0, stream>>>(
      aggr, hbf, wih, whh, mem, init_mem, lu, b_ih, b_hh,
      cnt, tmax, out_mem, out_lu, loss);
  k_fin  <<<1, 1, 0, stream>>>(loss, out_loss);
}

// Round 8
// 698.887 us; speedup vs baseline: 3.2667x; 1.0509x over previous
//
#include <hip/hip_runtime.h>
#include <math.h>

typedef float v4 __attribute__((ext_vector_type(4)));
typedef unsigned short us4 __attribute__((ext_vector_type(4)));
typedef unsigned short us8 __attribute__((ext_vector_type(8)));
typedef __bf16 bf16x8 __attribute__((ext_vector_type(8)));
typedef float f32x4 __attribute__((ext_vector_type(4)));

#define NN 100000   // nodes
#define NE 100000   // events
#define MD 128      // MEM_D
#define GD 384      // 3*MEM_D
#define MSGD 512    // MSG_D
#define NROWP 100032  // NN padded to 64 (tail block frag reads stay in-bounds)

// ws layout:
//   ints [0,NN) cnt | [NN,2NN) cur | [2NN,3NN) tmax | [3NN] total | [3NN+1] loss
//   ints [Z0,Z0+NN) offs | [Z0+NN,Z0+NN+3NE) entries       (ends at int 700032)
//   bf16 tenc [NE*64]      @ byte   2,800,128
//   bf16 aggrF[NROWP*512]  @ byte  15,600,128   (fragment order)
//   bf16 hbfF [NROWP*128]  @ byte 118,032,896   (fragment order)
//   bf16 wihF [384*512]    @ byte 143,641,088   (fragment order)
//   bf16 whhF [384*128]    @ byte 144,034,304   (ends 144,132,608)
#define Z0 300032

static __device__ inline unsigned short f2bf(float f) {
  unsigned u = __builtin_bit_cast(unsigned, f);
  u += 0x7fff + ((u >> 16) & 1);          // RNE
  return (unsigned short)(u >> 16);
}
static __device__ inline float bf2f(unsigned short s) {
  unsigned u = ((unsigned)s) << 16;
  return __builtin_bit_cast(float, u);
}

// Fragment-order offset for mfma_f32_16x16x32_bf16 operands.
// A-frag: lane l holds A[r0+(l&15)][k0+(l>>4)*8+i]; B uses r:=col (same map).
// off(r,k;K) = (((r>>4)*(K>>5) + (k>>5))*64 + (r&15) + ((k>>3)&3)*16)*8 + (k&7)
static __device__ inline size_t fragoff(int r, int k, int K) {
  return ((size_t)((r >> 4) * (K >> 5) + (k >> 5)) * 64
          + (r & 15) + ((k >> 3) & 3) * 16) * 8 + (k & 7);
}

// -------------------- CSR build: counts + segment-max(t) -------------------
__global__ __launch_bounds__(256)
void k_count(const int* __restrict__ src, const int* __restrict__ dst,
             const int* __restrict__ prod, const int* __restrict__ t,
             int* __restrict__ cnt, int* __restrict__ tmax)
{
  int e = blockIdx.x * 256 + threadIdx.x;
  if (e < NE) {
    int s = src[e], d = dst[e], p = prod[e], tt = t[e];
    atomicAdd(&cnt[s], 1); atomicAdd(&cnt[d], 1); atomicAdd(&cnt[p], 1);
    atomicMax(&tmax[s], tt); atomicMax(&tmax[d], tt); atomicMax(&tmax[p], tt);
  }
}

// -------------------- per-event time encoding (bf16 out) -------------------
__global__ __launch_bounds__(256)
void k_tenc(const int* __restrict__ src, const int* __restrict__ t,
            const int* __restrict__ lu,
            const float* __restrict__ W_t, const float* __restrict__ b_t,
            unsigned short* __restrict__ tenc)
{
  int gid = blockIdx.x * 256 + threadIdx.x;
  int e = gid >> 4, q = gid & 15;
  if (e < NE) {
    float tr = (float)(t[e] - lu[src[e]]);
    int j0 = q * 4;
    us4 o;
    o.x = f2bf(cosf(tr * W_t[j0 + 0] + b_t[j0 + 0]));
    o.y = f2bf(cosf(tr * W_t[j0 + 1] + b_t[j0 + 1]));
    o.z = f2bf(cosf(tr * W_t[j0 + 2] + b_t[j0 + 2]));
    o.w = f2bf(cosf(tr * W_t[j0 + 3] + b_t[j0 + 3]));
    *reinterpret_cast<us4*>(&tenc[(size_t)e * 64 + j0]) = o;
  }
}

// -------------------- segment offsets via wave-aggregated alloc ------------
__global__ __launch_bounds__(256)
void k_alloc(const int* __restrict__ cnt, int* __restrict__ offs,
             int* __restrict__ total)
{
  int g = blockIdx.x * 256 + threadIdx.x;
  int lane = threadIdx.x & 63;
  int val = (g < NN) ? cnt[g] : 0;
  int x = val;
  #pragma unroll
  for (int o = 1; o < 64; o <<= 1) {
    int y = __shfl_up(x, o);
    if (lane >= o) x += y;
  }
  int base = 0;
  if (lane == 63) base = atomicAdd(total, x);
  base = __shfl(base, 63);
  if (g < NN) offs[g] = base + x - val;
}

// -------------------- fill CSR entries -------------------------------------
__global__ __launch_bounds__(256)
void k_fill(const int* __restrict__ src, const int* __restrict__ dst,
            const int* __restrict__ prod,
            const int* __restrict__ offs, int* __restrict__ cur,
            int* __restrict__ entries)
{
  int e = blockIdx.x * 256 + threadIdx.x;
  if (e < NE) {
    int n, p;
    n = src[e];  p = atomicAdd(&cur[n], 1); entries[offs[n] + p] = e;
    n = dst[e];  p = atomicAdd(&cur[n], 1); entries[offs[n] + p] = e;
    n = prod[e]; p = atomicAdd(&cur[n], 1); entries[offs[n] + p] = e;
  }
}

// -------- bf16 conversions into FRAGMENT order: W_ih, W_hh, h --------------
__global__ __launch_bounds__(256)
void k_conv(const float* __restrict__ W_ih, const float* __restrict__ W_hh,
            const float* __restrict__ mem, const float* __restrict__ init_mem,
            const int* __restrict__ lu,
            unsigned short* __restrict__ wihF, unsigned short* __restrict__ whhF,
            unsigned short* __restrict__ hbfF)
{
  const int NWIH = 384 * 512 / 8;     // 24576
  const int NWHH = 384 * 128 / 8;     // 6144
  int gid = blockIdx.x * 256 + threadIdx.x;
  const float* s;
  unsigned short* o;
  if (gid < NWIH) {
    int col = gid >> 6, k0 = (gid & 63) * 8;
    s = W_ih + (size_t)col * MSGD + k0;
    o = wihF + fragoff(col, k0, MSGD);
  } else if (gid < NWIH + NWHH) {
    int idx = gid - NWIH;
    int col = idx >> 4, k0 = (idx & 15) * 8;
    s = W_hh + (size_t)col * MD + k0;
    o = whhF + fragoff(col, k0, MD);
  } else {
    int k = gid - NWIH - NWHH;   // [0, NN*16)
    int node = k >> 4, k0 = (k & 15) * 8;
    const float* hb = (lu[node] == -1) ? init_mem : mem;
    s = hb + (size_t)node * MD + k0;
    o = hbfF + fragoff(node, k0, MD);
  }
  v4 a0 = *reinterpret_cast<const v4*>(s);
  v4 a1 = *reinterpret_cast<const v4*>(s + 4);
  us8 u;
  u[0] = f2bf(a0.x); u[1] = f2bf(a0.y); u[2] = f2bf(a0.z); u[3] = f2bf(a0.w);
  u[4] = f2bf(a1.x); u[5] = f2bf(a1.y); u[6] = f2bf(a1.z); u[7] = f2bf(a1.w);
  *reinterpret_cast<us8*>(o) = u;
}

// ---------------------------------------------------------------------------
// Aggregation: thread = (node, v4-slot of 512-wide msg). Writes bf16 aggr
// in FRAGMENT order (8B us4 stores; L2 write-combines).
// ---------------------------------------------------------------------------
__global__ __launch_bounds__(256)
void k_aggr(const int* __restrict__ src, const int* __restrict__ dst,
            const int* __restrict__ prod,
            const float* __restrict__ raw, const float* __restrict__ mem,
            const unsigned short* __restrict__ tenc,
            const int* __restrict__ offs, const int* __restrict__ cnt,
            const int* __restrict__ entries,
            unsigned short* __restrict__ aggrF)
{
  const int tid = threadIdx.x;
  const int n = blockIdx.x * 2 + (tid >> 7);
  const int q = tid & 127;
  const int off = offs[n];
  const int len = cnt[n];

  v4 sum = {0.f, 0.f, 0.f, 0.f};
  if (q < 96) {
    const int* ridx = (q < 32) ? src : (q < 64) ? dst : prod;
    const int qc = q & 31;
    int e_cur = 0, row_cur = 0;
    if (len > 0) { e_cur = entries[off]; row_cur = ridx[e_cur]; }
    for (int k = 0; k < len; ++k) {
      int e_nxt = 0, row_nxt = 0;
      if (k + 1 < len) { e_nxt = entries[off + k + 1]; row_nxt = ridx[e_nxt]; }
      v4 v = *reinterpret_cast<const v4*>(mem + (size_t)row_cur * MD + qc * 4);
      sum.x += v.x; sum.y += v.y; sum.z += v.z; sum.w += v.w;
      e_cur = e_nxt; row_cur = row_nxt;
    }
    (void)e_cur;
  } else if (q < 112) {
    const int qc = q & 15;
    for (int k = 0; k < len; ++k) {
      int e = entries[off + k];
      v4 v = *reinterpret_cast<const v4*>(raw + (size_t)e * 64 + qc * 4);
      sum.x += v.x; sum.y += v.y; sum.z += v.z; sum.w += v.w;
    }
  } else {
    const int qc = q & 15;
    for (int k = 0; k < len; ++k) {
      int e = entries[off + k];
      us4 u = *reinterpret_cast<const us4*>(tenc + (size_t)e * 64 + qc * 4);
      sum.x += bf2f(u.x); sum.y += bf2f(u.y);
      sum.z += bf2f(u.z); sum.w += bf2f(u.w);
    }
  }
  float inv = 1.f / (float)max(len, 1);
  us4 o;
  o.x = f2bf(sum.x * inv); o.y = f2bf(sum.y * inv);
  o.z = f2bf(sum.z * inv); o.w = f2bf(sum.w * inv);
  *reinterpret_cast<us4*>(aggrF + fragoff(n, q * 4, MSGD)) = o;
}

// ---------------------------------------------------------------------------
// MFMA dual-GEMM + GRU.  Block = 256 threads = 4 waves, 64 nodes.
// All operands pre-swizzled to fragment order: every frag load is
// lane l <- base + l*16B  (fully coalesced, 1KB contiguous per instr).
// ---------------------------------------------------------------------------
__global__ __launch_bounds__(256)
void k_mfma(const unsigned short* __restrict__ aggrF,
            const unsigned short* __restrict__ hbfF,
            const unsigned short* __restrict__ wihF,
            const unsigned short* __restrict__ whhF,
            const float* __restrict__ mem, const float* __restrict__ init_mem,
            const int* __restrict__ lu,
            const float* __restrict__ b_ih, const float* __restrict__ b_hh,
            const int* __restrict__ cnt, const int* __restrict__ tmax,
            float* __restrict__ out_mem, float* __restrict__ out_lu,
            float* __restrict__ loss_acc)
{
  __shared__ float s_inv[64];
  __shared__ int s_sel[64], s_has[64];
  const int tid = threadIdx.x;
  const int n0 = blockIdx.x * 64;
  const int fb0 = n0 >> 4;            // first 16-row fragment block

  if (tid < 64) {
    int node = min(n0 + tid, NN - 1);
    int c = cnt[node];
    s_inv[tid] = 1.f / (float)max(c, 1);
    s_has[tid] = (c > 0);
    s_sel[tid] = (lu[node] == -1);
    if (n0 + tid < NN)
      out_lu[node] = (float)(c > 0 ? tmax[node] : lu[node]);
  }
  __syncthreads();

  const int w  = tid >> 6;
  const int l  = tid & 63;
  const int ln = l & 15;
  const int lg = l >> 4;

  f32x4 acc1[3][4][2];        // gates r,z,(i_n) x row-frag x d-frag
  f32x4 accNh[4][2];          // h_n
  #pragma unroll
  for (int g = 0; g < 3; ++g)
    #pragma unroll
    for (int rf = 0; rf < 4; ++rf)
      #pragma unroll
      for (int df = 0; df < 2; ++df)
        acc1[g][rf][df] = (f32x4){0.f, 0.f, 0.f, 0.f};
  #pragma unroll
  for (int rf = 0; rf < 4; ++rf)
    #pragma unroll
    for (int df = 0; df < 2; ++df)
      accNh[rf][df] = (f32x4){0.f, 0.f, 0.f, 0.f};

  // ---- GEMM1: gi = aggr @ W_ih^T   (K = 512, 16 k-steps)
  for (int ks = 0; ks < 16; ++ks) {
    bf16x8 a[4];
    #pragma unroll
    for (int rf = 0; rf < 4; ++rf)
      a[rf] = *reinterpret_cast<const bf16x8*>(
          aggrF + ((size_t)((fb0 + rf) * 16 + ks) * 64 + l) * 8);
    #pragma unroll
    for (int g = 0; g < 3; ++g) {
      #pragma unroll
      for (int df = 0; df < 2; ++df) {
        int cb = g * 8 + w * 2 + df;               // col block (16 cols)
        bf16x8 b = *reinterpret_cast<const bf16x8*>(
            wihF + ((size_t)(cb * 16 + ks) * 64 + l) * 8);
        #pragma unroll
        for (int rf = 0; rf < 4; ++rf)
          acc1[g][rf][df] = __builtin_amdgcn_mfma_f32_16x16x32_bf16(
              a[rf], b, acc1[g][rf][df], 0, 0, 0);
      }
    }
  }

  // ---- scale gi by 1/count (per output row; D row = (l>>4)*4+i)
  float inv[4][4];
  #pragma unroll
  for (int rf = 0; rf < 4; ++rf)
    #pragma unroll
    for (int i = 0; i < 4; ++i)
      inv[rf][i] = s_inv[rf * 16 + lg * 4 + i];
  #pragma unroll
  for (int g = 0; g < 3; ++g)
    #pragma unroll
    for (int rf = 0; rf < 4; ++rf)
      #pragma unroll
      for (int df = 0; df < 2; ++df)
        #pragma unroll
        for (int i = 0; i < 4; ++i)
          acc1[g][rf][df][i] *= inv[rf][i];

  // ---- GEMM2: gh = h @ W_hh^T   (K = 128, 4 k-steps); n-gate separate
  for (int ks = 0; ks < 4; ++ks) {
    bf16x8 a[4];
    #pragma unroll
    for (int rf = 0; rf < 4; ++rf)
      a[rf] = *reinterpret_cast<const bf16x8*>(
          hbfF + ((size_t)((fb0 + rf) * 4 + ks) * 64 + l) * 8);
    #pragma unroll
    for (int g = 0; g < 3; ++g) {
      #pragma unroll
      for (int df = 0; df < 2; ++df) {
        int cb = g * 8 + w * 2 + df;
        bf16x8 b = *reinterpret_cast<const bf16x8*>(
            whhF + ((size_t)(cb * 4 + ks) * 64 + l) * 8);
        if (g < 2) {
          #pragma unroll
          for (int rf = 0; rf < 4; ++rf)
            acc1[g][rf][df] = __builtin_amdgcn_mfma_f32_16x16x32_bf16(
                a[rf], b, acc1[g][rf][df], 0, 0, 0);
        } else {
          #pragma unroll
          for (int rf = 0; rf < 4; ++rf)
            accNh[rf][df] = __builtin_amdgcn_mfma_f32_16x16x32_bf16(
                a[rf], b, accNh[rf][df], 0, 0, 0);
        }
      }
    }
  }

  // ---- GRU epilogue (all gates in-lane)
  float ss = 0.f;
  #pragma unroll
  for (int df = 0; df < 2; ++df) {
    int d = w * 32 + df * 16 + ln;
    float bir = b_ih[d], biz = b_ih[128 + d], bin_ = b_ih[256 + d];
    float bhr = b_hh[d], bhz = b_hh[128 + d], bhn  = b_hh[256 + d];
    #pragma unroll
    for (int rf = 0; rf < 4; ++rf) {
      #pragma unroll
      for (int i = 0; i < 4; ++i) {
        int nloc = rf * 16 + lg * 4 + i;
        int node = n0 + nloc;
        if (node < NN) {
          const float* hb = s_sel[nloc] ? init_mem : mem;
          float hold = hb[(size_t)node * MD + d];
          float r  = 1.f / (1.f + expf(-(acc1[0][rf][df][i] + bir + bhr)));
          float z  = 1.f / (1.f + expf(-(acc1[1][rf][df][i] + biz + bhz)));
          float hn = accNh[rf][df][i] + bhn;
          float nn_ = tanhf(acc1[2][rf][df][i] + bin_ + r * hn);
          float nh = (1.f - z) * nn_ + z * hold;
          bool has = s_has[nloc] != 0;
          float o = has ? nh : hold;
          out_mem[(size_t)node * MD + d] = o;
          float dv = has ? (nh - hold) : 0.f;
          ss += dv * dv;
        }
      }
    }
  }
  #pragma unroll
  for (int off = 32; off > 0; off >>= 1)
    ss += __shfl_down(ss, off);
  if (l == 0) atomicAdd(loss_acc, ss);
}

__global__ void k_fin(const float* __restrict__ loss_acc, float* __restrict__ out_loss)
{
  out_loss[0] = sqrtf(loss_acc[0]) * (1.0f / (float)NN);
}

// ---------------------------------------------------------------------------
extern "C" void kernel_launch(void* const* d_in, const int* in_sizes, int n_in,
                              void* d_out, int out_size, void* d_ws, size_t ws_size,
                              hipStream_t stream)
{
  const int*   src      = (const int*)d_in[0];
  const int*   dst      = (const int*)d_in[1];
  const int*   prod     = (const int*)d_in[2];
  const int*   t        = (const int*)d_in[3];
  const float* raw      = (const float*)d_in[4];
  const float* mem      = (const float*)d_in[5];
  const int*   lu       = (const int*)d_in[6];
  const float* init_mem = (const float*)d_in[7];
  const float* W_t      = (const float*)d_in[8];
  const float* b_t      = (const float*)d_in[9];
  const float* W_ih     = (const float*)d_in[10];
  const float* W_hh     = (const float*)d_in[11];
  const float* b_ih     = (const float*)d_in[12];
  const float* b_hh     = (const float*)d_in[13];

  int* ws_i    = (int*)d_ws;
  int* cnt     = ws_i;
  int* cur     = ws_i + NN;
  int* tmax    = ws_i + 2 * NN;
  int* total   = ws_i + 3 * NN;
  float* loss  = (float*)(ws_i + 3 * NN + 1);
  int* offs    = ws_i + Z0;
  int* entries = offs + NN;
  unsigned short* tenc  = (unsigned short*)(entries + 3 * NE);      // byte 2,800,128
  unsigned short* aggrF = tenc  + (size_t)NE * 64;                  // byte 15,600,128
  unsigned short* hbfF  = aggrF + (size_t)NROWP * MSGD;             // byte 118,032,896
  unsigned short* wihF  = hbfF  + (size_t)NROWP * MD;               // byte 143,641,088
  unsigned short* whhF  = wihF  + (size_t)GD * MSGD;                // byte 144,034,304

  hipMemsetAsync(d_ws, 0, (size_t)(3 * NN + 2) * sizeof(int), stream);

  float* out_mem  = (float*)d_out;
  float* out_lu   = out_mem + (size_t)NN * MD;
  float* out_loss = out_lu + NN;

  k_count<<<(NE + 255) / 256, 256, 0, stream>>>(src, dst, prod, t, cnt, tmax);
  k_tenc <<<(NE * 16 + 255) / 256, 256, 0, stream>>>(src, t, lu, W_t, b_t, tenc);
  k_conv <<<(384 * 512 / 8 + 384 * 128 / 8 + NN * MD / 8 + 255) / 256, 256, 0, stream>>>(
      W_ih, W_hh, mem, init_mem, lu, wihF, whhF, hbfF);
  k_alloc<<<(NN + 255) / 256, 256, 0, stream>>>(cnt, offs, total);
  k_fill <<<(NE + 255) / 256, 256, 0, stream>>>(src, dst, prod, offs, cur, entries);
  k_aggr <<<NN / 2, 256, 0, stream>>>(src, dst, prod, raw, mem, tenc,
                                      offs, cnt, entries, aggrF);
  k_mfma <<<(NN + 63) / 64, 256, 0, stream>>>(
      aggrF, hbfF, wihF, whhF, mem, init_mem, lu, b_ih, b_hh,
      cnt, tmax, out_mem, out_lu, loss);
  k_fin  <<<1, 1, 0, stream>>>(loss, out_loss);
}